// Round 8
// baseline (6914.828 us; speedup 1.0000x reference)
//
#include <hip/hip_runtime.h>
#include <cmath>

// Problem constants
#define NTAG    12
#define TAG_START 10
#define TAG_STOP  11
#define NEGV    (-10000.0f)

// k_lstm weight residency split (of 128 j-quads)
#define JREG 44
#define JLDS 16
#define JSTR (128 - JREG - JLDS)   // 68

typedef unsigned int uint32;
typedef unsigned short u16;
typedef __attribute__((ext_vector_type(8))) short bf16x8;
typedef __attribute__((ext_vector_type(4))) float f32x4;

#if defined(__has_builtin)
# if __has_builtin(__builtin_amdgcn_sdot4)
#  define HAVE_SDOT4 1
# endif
#endif

#ifdef HAVE_SDOT4
#define SDOT4(a, b, c) __builtin_amdgcn_sdot4((int)(a), (int)(b), (c), false)
#else
__device__ inline int sdot4_sw(uint32 a, uint32 b, int c) {
    int r = c;
    r += ((int)(a << 24) >> 24) * ((int)(b << 24) >> 24);
    r += ((int)(a << 16) >> 24) * ((int)(b << 16) >> 24);
    r += ((int)(a << 8)  >> 24) * ((int)(b << 8)  >> 24);
    r += ((int)a >> 24)         * ((int)b >> 24);
    return r;
}
#define SDOT4(a, b, c) sdot4_sw((a), (b), (c))
#endif

// bf16 <-> f32 helpers
__device__ inline float b2f(u16 h) {
    union { uint32 u; float f; } v; v.u = ((uint32)h) << 16; return v.f;
}
__device__ inline u16 f2b(float f) {
    union { float f; uint32 u; } v; v.f = f;
    uint32 u = v.u;
    uint32 r = (u + 0x7FFFu + ((u >> 16) & 1u)) >> 16;
    return (u16)r;
}
__device__ inline uint32 f2b2(float a, float b) {
    return (uint32)f2b(a) | ((uint32)f2b(b) << 16);
}
__device__ inline float flo(uint32 u) {
    union { uint32 u; float f; } v; v.u = u << 16; return v.f;
}
__device__ inline float fhi(uint32 u) {
    union { uint32 u; float f; } v; v.u = u & 0xFFFF0000u; return v.f;
}

// ---------------------------------------------------------------------------
// ws layout (bytes):
//   Wq      u32 [2 dir][128 jq][2048 g]   2,097,152   int8 K-quad W_hh^T
//   s127    f32 [2][2048]                    16,384   per-row scale / 127
//   Wihb    u16 [4096][512]               4,194,304   bf16 W_ih (f then b)
//   biascat f32 [4096]                       16,384   bias (f then b)
//   Ft      f32 [32768][12]               1,572,864   feats
//   Lout    bf16 [32768][1024]           67,108,864   bilstm output
//   Gx      bf16 [NB*512][4096]       NB*4,194,304    gate preacts (chunk)
// ---------------------------------------------------------------------------

// --- Kernel 0: pack W_ih + bias to bf16 concat -------------------------------
__global__ __launch_bounds__(256) void k_packw(const float* __restrict__ Wf,
        const float* __restrict__ Wb, const float* __restrict__ bf,
        const float* __restrict__ bb, u16* __restrict__ Wihb,
        float* __restrict__ biascat) {
    int g = blockIdx.x;           // 0..4095
    const float* src = (g < 2048) ? (Wf + (size_t)g * 512)
                                  : (Wb + (size_t)(g - 2048) * 512);
    for (int k = threadIdx.x; k < 512; k += 256)
        Wihb[(size_t)g * 512 + k] = f2b(src[k]);
    if (threadIdx.x == 0)
        biascat[g] = (g < 2048) ? bf[g] : bb[g - 2048];
}

// --- Kernel 1: int8 quantize+pack W_hh ---------------------------------------
__global__ __launch_bounds__(64) void k_pack(const float* __restrict__ Wf,
                                             const float* __restrict__ Wb,
                                             uint32* __restrict__ Wq,
                                             float* __restrict__ s127) {
    int e = blockIdx.x;                 // 0..4095
    int dir = e >> 11, g = e & 2047;
    const float* W = (dir ? Wb : Wf) + (size_t)g * 512;
    int t = threadIdx.x;
    float w[8];
    float m = 0.f;
    #pragma unroll
    for (int i = 0; i < 8; ++i) {
        w[i] = W[t * 8 + i];
        m = fmaxf(m, fabsf(w[i]));
    }
    #pragma unroll
    for (int off = 32; off > 0; off >>= 1)
        m = fmaxf(m, __shfl_xor(m, off));
    float s = (m > 0.f) ? (m / 127.f) : 1.f;
    float inv = 1.f / s;
    uint32 d0 = 0, d1 = 0;
    #pragma unroll
    for (int i = 0; i < 4; ++i) {
        uint32 q0 = (uint32)((int)rintf(w[i] * inv)) & 0xFFu;
        uint32 q1 = (uint32)((int)rintf(w[4 + i] * inv)) & 0xFFu;
        d0 |= q0 << (8 * i);
        d1 |= q1 << (8 * i);
    }
    Wq[((size_t)(dir * 128) + (t << 1)) * 2048 + g] = d0;
    Wq[((size_t)(dir * 128) + (t << 1) + 1) * 2048 + g] = d1;
    if (t == 0) s127[dir * 2048 + g] = s / 127.f;
}

// --- Kernel 2: fused gather + input GEMM, bf16 MFMA (unchanged) -------------
__global__ __launch_bounds__(256) void k_gemm(const int* __restrict__ sent,
        const float* __restrict__ emb, const u16* __restrict__ Wihb,
        const float* __restrict__ biascat, u16* __restrict__ Gxc, int b0c) {
    __shared__ __align__(16) u16 As[128][72];
    __shared__ __align__(16) u16 Bs[128][72];
    __shared__ int ssent[128];

    int bid = blockIdx.x;
    int nb = bid & 31, mb = bid >> 5;
    int M0 = mb << 7, N0 = nb << 7;
    int t = threadIdx.x;
    int w = t >> 6, l = t & 63;
    int wr = w >> 1, wc = w & 1;

    if (t < 128) ssent[t] = sent[b0c * 512 + M0 + t];

    f32x4 zero = {0.f, 0.f, 0.f, 0.f};
    f32x4 acc[4][4];
    #pragma unroll
    for (int i = 0; i < 4; ++i)
        #pragma unroll
        for (int j = 0; j < 4; ++j) acc[i][j] = zero;

    int srow = t >> 3;
    int skc  = (t & 7) << 3;
    __syncthreads();

    for (int k0 = 0; k0 < 512; k0 += 64) {
        #pragma unroll
        for (int i = 0; i < 4; ++i) {
            int r = srow + (i << 5);
            const float* srcA = emb + (size_t)ssent[r] * 512 + k0 + skc;
            float4 f0 = *(const float4*)srcA;
            float4 f1 = *(const float4*)(srcA + 4);
            uint4 pa;
            pa.x = f2b2(f0.x, f0.y); pa.y = f2b2(f0.z, f0.w);
            pa.z = f2b2(f1.x, f1.y); pa.w = f2b2(f1.z, f1.w);
            *(uint4*)&As[r][skc] = pa;
            uint4 pb = *(const uint4*)(Wihb + (size_t)(N0 + r) * 512 + k0 + skc);
            *(uint4*)&Bs[r][skc] = pb;
        }
        __syncthreads();
        int lrow = l & 15, lk = (l >> 4) << 3;
        #pragma unroll
        for (int kk = 0; kk < 64; kk += 32) {
            bf16x8 af[4], bfr[4];
            #pragma unroll
            for (int i = 0; i < 4; ++i)
                af[i] = *(const bf16x8*)&As[(wr << 6) + (i << 4) + lrow][kk + lk];
            #pragma unroll
            for (int j = 0; j < 4; ++j)
                bfr[j] = *(const bf16x8*)&Bs[(wc << 6) + (j << 4) + lrow][kk + lk];
            #pragma unroll
            for (int i = 0; i < 4; ++i)
                #pragma unroll
                for (int j = 0; j < 4; ++j)
                    acc[i][j] = __builtin_amdgcn_mfma_f32_16x16x32_bf16(
                        af[i], bfr[j], acc[i][j], 0, 0, 0);
        }
        __syncthreads();
    }

    int lrow = l & 15, lq = l >> 4;
    #pragma unroll
    for (int j = 0; j < 4; ++j) {
        int col = N0 + (wc << 6) + (j << 4) + lrow;
        float bv = biascat[col];
        #pragma unroll
        for (int i = 0; i < 4; ++i) {
            int rbase = M0 + (wr << 6) + (i << 4) + (lq << 2);
            #pragma unroll
            for (int r = 0; r < 4; ++r)
                Gxc[(size_t)(rbase + r) * 4096 + col] = f2b(acc[i][j][r] + bv);
        }
    }
}

// --- Kernel 3: BiLSTM recurrence, 3-tier resident int8 weights + sdot4 ------
// One block = (2 batches, 1 dir); 1 block/CU so launch_bounds(512,1) gives the
// allocator the full 256-VGPR budget (r7's (512,2) capped it at 128 and the
// register tier silently re-streamed).
__global__ __launch_bounds__(512, 1) void k_lstm(const u16* __restrict__ Gxc,
        const uint32* __restrict__ Wq, const float* __restrict__ s127,
        u16* __restrict__ Lout, int b0c) {
    int dir, slot;
    if (gridDim.x >= 8) {
        int xid = blockIdx.x & 7, q = blockIdx.x >> 3;
        dir  = xid >> 2;
        slot = (xid & 3) | (q << 2);
    } else {
        dir  = blockIdx.x & 1;
        slot = blockIdx.x >> 1;
    }
    int b0  = b0c + (slot << 1);
    int lb0 = slot << 1;

    __shared__ __align__(16) uint32 wlds[JLDS][2048]; // 128 KB LDS-resident weights
    __shared__ __align__(16) uint32 hq[2][128];       // i8-packed h
    __shared__ __align__(16) float  gb[2][2048];      // gate preacts

    int t = threadIdx.x;
    if (t < 256) hq[t >> 7][t & 127] = 0u;
    float csr0 = 0.f, csr1 = 0.f;                     // cell state (unit t)

    const uint32* wsrc = Wq + (size_t)dir * (128 * 2048);
    // preload LDS tier (coalesced uint4 copy)
    {
        const uint4* src = (const uint4*)(wsrc + (size_t)JREG * 2048);
        uint4* dst = (uint4*)wlds;
        #pragma unroll
        for (int i = 0; i < JLDS; ++i)
            dst[t + i * 512] = src[t + i * 512];
    }
    // preload VGPR tier (static index only — stays in registers)
    int g4 = t << 2;
    const uint32* wp = wsrc + g4;
    uint4 wreg[JREG];
    #pragma unroll
    for (int i = 0; i < JREG; ++i)
        wreg[i] = *(const uint4*)(wp + (size_t)i * 2048);

    float4 sc = *(const float4*)(s127 + dir * 2048 + g4);
    const u16* gxb0 = Gxc + (size_t)lb0 * 512 * 4096 + (dir << 11) + g4;
    const u16* gxb1 = gxb0 + (size_t)512 * 4096;
    const uint32* spB = wsrc + (size_t)(JREG + JLDS) * 2048 + g4;
    __syncthreads();

    for (int si = 0; si < 512; ++si) {
        int s = dir ? (511 - si) : si;
        ushort4 q0 = *(const ushort4*)(gxb0 + (size_t)s * 4096);
        ushort4 q1 = *(const ushort4*)(gxb1 + (size_t)s * 4096);

        int a00 = 0, a01 = 0, a02 = 0, a03 = 0;
        int a10 = 0, a11 = 0, a12 = 0, a13 = 0;

        // tier 1: VGPR-resident (fully unrolled, static indices)
        #pragma unroll
        for (int i = 0; i < JREG; ++i) {
            uint4 wv = wreg[i];
            uint32 h0 = hq[0][i];
            uint32 h1 = hq[1][i];
            a00 = SDOT4(h0, wv.x, a00); a01 = SDOT4(h0, wv.y, a01);
            a02 = SDOT4(h0, wv.z, a02); a03 = SDOT4(h0, wv.w, a03);
            a10 = SDOT4(h1, wv.x, a10); a11 = SDOT4(h1, wv.y, a11);
            a12 = SDOT4(h1, wv.z, a12); a13 = SDOT4(h1, wv.w, a13);
        }
        // tier 2: LDS-resident
        #pragma unroll
        for (int i = 0; i < JLDS; ++i) {
            uint4 wv = *(const uint4*)&wlds[i][g4];
            uint32 h0 = hq[0][JREG + i];
            uint32 h1 = hq[1][JREG + i];
            a00 = SDOT4(h0, wv.x, a00); a01 = SDOT4(h0, wv.y, a01);
            a02 = SDOT4(h0, wv.z, a02); a03 = SDOT4(h0, wv.w, a03);
            a10 = SDOT4(h1, wv.x, a10); a11 = SDOT4(h1, wv.y, a11);
            a12 = SDOT4(h1, wv.z, a12); a13 = SDOT4(h1, wv.w, a13);
        }
        // tier 3: streamed from L2
        #pragma unroll 4
        for (int i = 0; i < JSTR; ++i) {
            uint4 wv = *(const uint4*)(spB + (size_t)i * 2048);
            uint32 h0 = hq[0][JREG + JLDS + i];
            uint32 h1 = hq[1][JREG + JLDS + i];
            a00 = SDOT4(h0, wv.x, a00); a01 = SDOT4(h0, wv.y, a01);
            a02 = SDOT4(h0, wv.z, a02); a03 = SDOT4(h0, wv.w, a03);
            a10 = SDOT4(h1, wv.x, a10); a11 = SDOT4(h1, wv.y, a11);
            a12 = SDOT4(h1, wv.z, a12); a13 = SDOT4(h1, wv.w, a13);
        }

        float4 p0 = make_float4(b2f(q0.x) + sc.x * (float)a00,
                                b2f(q0.y) + sc.y * (float)a01,
                                b2f(q0.z) + sc.z * (float)a02,
                                b2f(q0.w) + sc.w * (float)a03);
        float4 p1 = make_float4(b2f(q1.x) + sc.x * (float)a10,
                                b2f(q1.y) + sc.y * (float)a11,
                                b2f(q1.z) + sc.z * (float)a12,
                                b2f(q1.w) + sc.w * (float)a13);
        *(float4*)&gb[0][g4] = p0;
        *(float4*)&gb[1][g4] = p1;
        __syncthreads();

        // activation: thread t = unit t, both batches; c in registers
        {
            float gi = gb[0][t];
            float gf = gb[0][512 + t];
            float gg = gb[0][1024 + t];
            float go = gb[0][1536 + t];
            float iv  = 1.f / (1.f + expf(-gi));
            float fvv = 1.f / (1.f + expf(-gf));
            float gv  = tanhf(gg);
            float ov  = 1.f / (1.f + expf(-go));
            float cn = fvv * csr0 + iv * gv;
            float hn = ov * tanhf(cn);
            csr0 = cn;
            ((signed char*)hq[0])[t] = (signed char)(int)rintf(hn * 127.f);
            Lout[((size_t)(b0 + 0) * 512 + s) * 1024 + (dir << 9) + t] = f2b(hn);
        }
        {
            float gi = gb[1][t];
            float gf = gb[1][512 + t];
            float gg = gb[1][1024 + t];
            float go = gb[1][1536 + t];
            float iv  = 1.f / (1.f + expf(-gi));
            float fvv = 1.f / (1.f + expf(-gf));
            float gv  = tanhf(gg);
            float ov  = 1.f / (1.f + expf(-go));
            float cn = fvv * csr1 + iv * gv;
            float hn = ov * tanhf(cn);
            csr1 = cn;
            ((signed char*)hq[1])[t] = (signed char)(int)rintf(hn * 127.f);
            Lout[((size_t)(b0 + 1) * 512 + s) * 1024 + (dir << 9) + t] = f2b(hn);
        }
        __syncthreads();
    }
}

// --- Kernel 4: feats = Lout(bf16) @ W_out^T + b_out ------------------------
__global__ __launch_bounds__(256) void k_feats(const u16* __restrict__ Lout,
        const float* __restrict__ Wout, const float* __restrict__ bout,
        float* __restrict__ Ft) {
    __shared__ __align__(16) float Wl[12 * 1024];
    for (int i = threadIdx.x; i < 12 * 1024; i += 256) Wl[i] = Wout[i];
    __syncthreads();
    int wv = threadIdx.x >> 6, lane = threadIdx.x & 63;
    size_t row = (size_t)blockIdx.x * 4 + wv;
    const uint4* xr = (const uint4*)(Lout + row * 1024);
    float acc[12];
    #pragma unroll
    for (int tg = 0; tg < 12; ++tg) acc[tg] = 0.f;
    #pragma unroll
    for (int c = 0; c < 2; ++c) {
        int e8 = lane + (c << 6);
        uint4 xv = xr[e8];
        float x0 = flo(xv.x), x1 = fhi(xv.x);
        float x2 = flo(xv.y), x3 = fhi(xv.y);
        float x4 = flo(xv.z), x5 = fhi(xv.z);
        float x6 = flo(xv.w), x7 = fhi(xv.w);
        #pragma unroll
        for (int tg = 0; tg < 12; ++tg) {
            const float* wpt = &Wl[tg * 1024 + (e8 << 3)];
            float4 wa = *(const float4*)wpt;
            float4 wb = *(const float4*)(wpt + 4);
            acc[tg] += x0 * wa.x + x1 * wa.y + x2 * wa.z + x3 * wa.w
                     + x4 * wb.x + x5 * wb.y + x6 * wb.z + x7 * wb.w;
        }
    }
    #pragma unroll
    for (int tg = 0; tg < 12; ++tg) {
        #pragma unroll
        for (int off = 32; off > 0; off >>= 1)
            acc[tg] += __shfl_xor(acc[tg], off);
    }
    float v = 0.f;
    #pragma unroll
    for (int tg = 0; tg < 12; ++tg)
        if (lane == tg) v = acc[tg];
    if (lane < 12) Ft[row * 12 + lane] = v + bout[lane];
}

// --- Kernel 5: Viterbi per batch (1 wave). ---------------------------------
__global__ __launch_bounds__(64) void k_viterbi(const float* __restrict__ Ft,
        const float* __restrict__ trans, float* __restrict__ out) {
    int b = blockIdx.x;
    int lane = threadIdx.x;
    __shared__ unsigned char bps[512][12];
    float tr[12];
    #pragma unroll
    for (int p = 0; p < 12; ++p)
        tr[p] = (lane < 12) ? trans[lane * 12 + p] : 0.f;
    float fv = (lane == TAG_START) ? 0.f : NEGV;
    const float* fb = Ft + (size_t)b * 512 * 12;
    for (int s = 0; s < 512; ++s) {
        float m = -3.4e38f;
        int bp = 0;
        #pragma unroll
        for (int p = 0; p < 12; ++p) {
            float v = __shfl(fv, p) + tr[p];
            if (v > m) { m = v; bp = p; }
        }
        float feat = (lane < 12) ? fb[s * 12 + lane] : 0.f;
        fv = m + feat;
        if (lane < 12) bps[s][lane] = (unsigned char)bp;
    }
    float term = fv + ((lane < 12) ? trans[TAG_STOP * 12 + lane] : 0.f);
    __syncthreads();
    float best = -3.4e38f; int tag = 0;
    #pragma unroll
    for (int p = 0; p < 12; ++p) {
        float v = __shfl(term, p);
        if (v > best) { best = v; tag = p; }
    }
    if (lane == 0) {
        out[b] = best;
        int tg = tag;
        for (int s = 511; s >= 0; --s) {
            out[64 + (size_t)b * 512 + s] = (float)tg;
            tg = bps[s][tg];
        }
    }
}

extern "C" void kernel_launch(void* const* d_in, const int* in_sizes, int n_in,
                              void* d_out, int out_size, void* d_ws, size_t ws_size,
                              hipStream_t stream) {
    const int*   sent   = (const int*)  d_in[0];
    const float* emb    = (const float*)d_in[1];
    const float* W_ih_f = (const float*)d_in[2];
    const float* W_hh_f = (const float*)d_in[3];
    const float* b_f    = (const float*)d_in[4];
    const float* W_ih_b = (const float*)d_in[5];
    const float* W_hh_b = (const float*)d_in[6];
    const float* b_b    = (const float*)d_in[7];
    const float* W_out  = (const float*)d_in[8];
    const float* b_out  = (const float*)d_in[9];
    const float* trans  = (const float*)d_in[10];
    float* out = (float*)d_out;

    char* wsB = (char*)d_ws;
    size_t off = 0;
    uint32* Wq     = (uint32*)(wsB + off); off += 2097152;
    float*  s127   = (float*) (wsB + off); off += 16384;
    u16*    Wihb   = (u16*)   (wsB + off); off += 4194304;
    float*  biascat= (float*) (wsB + off); off += 16384;
    float*  Ft     = (float*) (wsB + off); off += 1572864;
    u16*    Lout   = (u16*)   (wsB + off); off += 67108864;
    size_t fixed = off;
    u16*    Gxc    = (u16*)   (wsB + off);

    int NB = 64;
    while (NB > 2 && fixed + (size_t)NB * 4194304ull > ws_size) NB >>= 1;

    k_packw<<<4096, 256, 0, stream>>>(W_ih_f, W_ih_b, b_f, b_b, Wihb, biascat);
    k_pack <<<4096, 64, 0, stream>>>(W_hh_f, W_hh_b, Wq, s127);
    for (int c = 0; c < 64; c += NB) {
        k_gemm<<<NB * 128, 256, 0, stream>>>(sent, emb, Wihb, biascat, Gxc, c);
        k_lstm<<<NB, 512, 0, stream>>>(Gxc, Wq, s127, Lout, c);
    }
    k_feats  <<<8192, 256, 0, stream>>>(Lout, W_out, b_out, Ft);
    k_viterbi<<<64, 64, 0, stream>>>(Ft, trans, out);
}

// Round 9
// 5349.442 us; speedup vs baseline: 1.2926x; 1.2926x over previous
//
#include <hip/hip_runtime.h>
#include <cmath>

// Problem constants
#define NTAG    12
#define TAG_START 10
#define TAG_STOP  11
#define NEGV    (-10000.0f)

// k_lstm: of 64 j-octs, this many LDS-resident (rest streamed from L2)
#define JO_LDS 16

typedef unsigned int uint32;
typedef unsigned short u16;
typedef __attribute__((ext_vector_type(8))) short bf16x8;
typedef __attribute__((ext_vector_type(4))) float f32x4;

#if defined(__has_builtin)
# if __has_builtin(__builtin_amdgcn_sdot4)
#  define HAVE_SDOT4 1
# endif
#endif

#ifdef HAVE_SDOT4
#define SDOT4(a, b, c) __builtin_amdgcn_sdot4((int)(a), (int)(b), (c), false)
#else
__device__ inline int sdot4_sw(uint32 a, uint32 b, int c) {
    int r = c;
    r += ((int)(a << 24) >> 24) * ((int)(b << 24) >> 24);
    r += ((int)(a << 16) >> 24) * ((int)(b << 16) >> 24);
    r += ((int)(a << 8)  >> 24) * ((int)(b << 8)  >> 24);
    r += ((int)a >> 24)         * ((int)b >> 24);
    return r;
}
#define SDOT4(a, b, c) sdot4_sw((a), (b), (c))
#endif

// bf16 <-> f32 helpers
__device__ inline float b2f(u16 h) {
    union { uint32 u; float f; } v; v.u = ((uint32)h) << 16; return v.f;
}
__device__ inline u16 f2b(float f) {
    union { float f; uint32 u; } v; v.f = f;
    uint32 u = v.u;
    uint32 r = (u + 0x7FFFu + ((u >> 16) & 1u)) >> 16;
    return (u16)r;
}
__device__ inline uint32 f2b2(float a, float b) {
    return (uint32)f2b(a) | ((uint32)f2b(b) << 16);
}
__device__ inline float flo(uint32 u) {
    union { uint32 u; float f; } v; v.u = u << 16; return v.f;
}
__device__ inline float fhi(uint32 u) {
    union { uint32 u; float f; } v; v.u = u & 0xFFFF0000u; return v.f;
}

// ---------------------------------------------------------------------------
// ws layout (bytes):
//   Wn      u32 [2 dir][64 oct][2048 g]   1,048,576   int4 W_hh^T (nibble-packed)
//   s127n   f32 [2][2048]                    16,384   per-row scale/(127*16)
//   Wihb    u16 [4096][512]               4,194,304   bf16 W_ih (f then b)
//   biascat f32 [4096]                       16,384   bias (f then b)
//   Ft      f32 [32768][12]               1,572,864   feats
//   Lout    bf16 [32768][1024]           67,108,864   bilstm output
//   Gx      bf16 [NB*512][4096]       NB*4,194,304    gate preacts (chunk)
// ---------------------------------------------------------------------------

// --- Kernel 0: pack W_ih + bias to bf16 concat -------------------------------
__global__ __launch_bounds__(256) void k_packw(const float* __restrict__ Wf,
        const float* __restrict__ Wb, const float* __restrict__ bf,
        const float* __restrict__ bb, u16* __restrict__ Wihb,
        float* __restrict__ biascat) {
    int g = blockIdx.x;           // 0..4095
    const float* src = (g < 2048) ? (Wf + (size_t)g * 512)
                                  : (Wb + (size_t)(g - 2048) * 512);
    for (int k = threadIdx.x; k < 512; k += 256)
        Wihb[(size_t)g * 512 + k] = f2b(src[k]);
    if (threadIdx.x == 0)
        biascat[g] = (g < 2048) ? bf[g] : bb[g - 2048];
}

// --- Kernel 1: int4 quantize+pack W_hh. One wave per (dir, gate row). --------
// Oct o of row g -> dword at Wn[(dir*64+o)*2048+g]:
//   byte k = (q[w[8o+k]] & 0xF) | (q[w[8o+4+k]] << 4),  q = rint(w*7/max|row|)
__global__ __launch_bounds__(64) void k_pack(const float* __restrict__ Wf,
                                             const float* __restrict__ Wb,
                                             uint32* __restrict__ Wn,
                                             float* __restrict__ s127n) {
    int e = blockIdx.x;                 // 0..4095
    int dir = e >> 11, g = e & 2047;
    const float* W = (dir ? Wb : Wf) + (size_t)g * 512;
    int t = threadIdx.x;                // oct index
    float w[8];
    float m = 0.f;
    #pragma unroll
    for (int i = 0; i < 8; ++i) {
        w[i] = W[t * 8 + i];
        m = fmaxf(m, fabsf(w[i]));
    }
    #pragma unroll
    for (int off = 32; off > 0; off >>= 1)
        m = fmaxf(m, __shfl_xor(m, off));
    float s = (m > 0.f) ? (m / 7.f) : 1.f;
    float inv = 1.f / s;
    uint32 d = 0;
    #pragma unroll
    for (int k = 0; k < 4; ++k) {
        uint32 qlo = (uint32)((int)rintf(w[k] * inv)) & 0xFu;
        uint32 qhi = (uint32)((int)rintf(w[4 + k] * inv)) & 0xFu;
        d |= (qlo | (qhi << 4)) << (8 * k);
    }
    Wn[((size_t)(dir * 64) + t) * 2048 + g] = d;
    if (t == 0) s127n[dir * 2048 + g] = s / (127.f * 16.f);
}

// --- Kernel 2: fused gather + input GEMM, bf16 MFMA (unchanged) -------------
__global__ __launch_bounds__(256) void k_gemm(const int* __restrict__ sent,
        const float* __restrict__ emb, const u16* __restrict__ Wihb,
        const float* __restrict__ biascat, u16* __restrict__ Gxc, int b0c) {
    __shared__ __align__(16) u16 As[128][72];
    __shared__ __align__(16) u16 Bs[128][72];
    __shared__ int ssent[128];

    int bid = blockIdx.x;
    int nb = bid & 31, mb = bid >> 5;
    int M0 = mb << 7, N0 = nb << 7;
    int t = threadIdx.x;
    int w = t >> 6, l = t & 63;
    int wr = w >> 1, wc = w & 1;

    if (t < 128) ssent[t] = sent[b0c * 512 + M0 + t];

    f32x4 zero = {0.f, 0.f, 0.f, 0.f};
    f32x4 acc[4][4];
    #pragma unroll
    for (int i = 0; i < 4; ++i)
        #pragma unroll
        for (int j = 0; j < 4; ++j) acc[i][j] = zero;

    int srow = t >> 3;
    int skc  = (t & 7) << 3;
    __syncthreads();

    for (int k0 = 0; k0 < 512; k0 += 64) {
        #pragma unroll
        for (int i = 0; i < 4; ++i) {
            int r = srow + (i << 5);
            const float* srcA = emb + (size_t)ssent[r] * 512 + k0 + skc;
            float4 f0 = *(const float4*)srcA;
            float4 f1 = *(const float4*)(srcA + 4);
            uint4 pa;
            pa.x = f2b2(f0.x, f0.y); pa.y = f2b2(f0.z, f0.w);
            pa.z = f2b2(f1.x, f1.y); pa.w = f2b2(f1.z, f1.w);
            *(uint4*)&As[r][skc] = pa;
            uint4 pb = *(const uint4*)(Wihb + (size_t)(N0 + r) * 512 + k0 + skc);
            *(uint4*)&Bs[r][skc] = pb;
        }
        __syncthreads();
        int lrow = l & 15, lk = (l >> 4) << 3;
        #pragma unroll
        for (int kk = 0; kk < 64; kk += 32) {
            bf16x8 af[4], bfr[4];
            #pragma unroll
            for (int i = 0; i < 4; ++i)
                af[i] = *(const bf16x8*)&As[(wr << 6) + (i << 4) + lrow][kk + lk];
            #pragma unroll
            for (int j = 0; j < 4; ++j)
                bfr[j] = *(const bf16x8*)&Bs[(wc << 6) + (j << 4) + lrow][kk + lk];
            #pragma unroll
            for (int i = 0; i < 4; ++i)
                #pragma unroll
                for (int j = 0; j < 4; ++j)
                    acc[i][j] = __builtin_amdgcn_mfma_f32_16x16x32_bf16(
                        af[i], bfr[j], acc[i][j], 0, 0, 0);
        }
        __syncthreads();
    }

    int lrow = l & 15, lq = l >> 4;
    #pragma unroll
    for (int j = 0; j < 4; ++j) {
        int col = N0 + (wc << 6) + (j << 4) + lrow;
        float bv = biascat[col];
        #pragma unroll
        for (int i = 0; i < 4; ++i) {
            int rbase = M0 + (wr << 6) + (i << 4) + (lq << 2);
            #pragma unroll
            for (int r = 0; r < 4; ++r)
                Gxc[(size_t)(rbase + r) * 4096 + col] = f2b(acc[i][j][r] + bv);
        }
    }
}

// --- Kernel 3: BiLSTM recurrence, int4 weights (LDS tier + L2 stream) -------
// One block = (2 batches, 1 dir). Octs 0..JO_LDS-1 LDS-resident, rest streamed.
// Nibble unpack: lo=(w<<4)&0xF0F0F0F0, hi=w&0xF0F0F0F0 -> bytes = 16*q (exact);
// the 16 is folded into s127n.
__global__ __launch_bounds__(512, 2) void k_lstm(const u16* __restrict__ Gxc,
        const uint32* __restrict__ Wn, const float* __restrict__ s127n,
        u16* __restrict__ Lout, int b0c) {
    int dir, slot;
    if (gridDim.x >= 8) {
        int xid = blockIdx.x & 7, q = blockIdx.x >> 3;
        dir  = xid >> 2;
        slot = (xid & 3) | (q << 2);
    } else {
        dir  = blockIdx.x & 1;
        slot = blockIdx.x >> 1;
    }
    int b0  = b0c + (slot << 1);
    int lb0 = slot << 1;

    __shared__ __align__(16) uint32 wlds[JO_LDS][2048]; // 128 KB int4 weights
    __shared__ __align__(16) uint32 hq[2][128];         // i8-packed h
    __shared__ __align__(16) float  gb[2][2048];        // gate preacts

    int t = threadIdx.x;
    if (t < 256) hq[t >> 7][t & 127] = 0u;
    float csr0 = 0.f, csr1 = 0.f;

    const uint32* wsrc = Wn + (size_t)dir * (64 * 2048);
    {   // preload LDS tier (coalesced uint4 copy: JO_LDS*2048/4 = JO_LDS*512 uint4)
        const uint4* src = (const uint4*)wsrc;
        uint4* dst = (uint4*)wlds;
        #pragma unroll
        for (int i = 0; i < JO_LDS; ++i)
            dst[t + i * 512] = src[t + i * 512];
    }
    int g4 = t << 2;
    float4 sc = *(const float4*)(s127n + dir * 2048 + g4);
    const u16* gxb0 = Gxc + (size_t)lb0 * 512 * 4096 + (dir << 11) + g4;
    const u16* gxb1 = gxb0 + (size_t)512 * 4096;
    const uint32* spB = wsrc + (size_t)JO_LDS * 2048 + g4;
    __syncthreads();

    for (int si = 0; si < 512; ++si) {
        int s = dir ? (511 - si) : si;
        ushort4 q0 = *(const ushort4*)(gxb0 + (size_t)s * 4096);
        ushort4 q1 = *(const ushort4*)(gxb1 + (size_t)s * 4096);

        int a00 = 0, a01 = 0, a02 = 0, a03 = 0;
        int a10 = 0, a11 = 0, a12 = 0, a13 = 0;

        // tier 1: LDS-resident octs
        #pragma unroll
        for (int o = 0; o < JO_LDS; ++o) {
            uint4 wv = *(const uint4*)&wlds[o][g4];
            uint32 hA0 = hq[0][2 * o], hB0 = hq[0][2 * o + 1];
            uint32 hA1 = hq[1][2 * o], hB1 = hq[1][2 * o + 1];
            uint32 lo, hi;
            lo = (wv.x << 4) & 0xF0F0F0F0u; hi = wv.x & 0xF0F0F0F0u;
            a00 = SDOT4(hA0, lo, a00); a00 = SDOT4(hB0, hi, a00);
            a10 = SDOT4(hA1, lo, a10); a10 = SDOT4(hB1, hi, a10);
            lo = (wv.y << 4) & 0xF0F0F0F0u; hi = wv.y & 0xF0F0F0F0u;
            a01 = SDOT4(hA0, lo, a01); a01 = SDOT4(hB0, hi, a01);
            a11 = SDOT4(hA1, lo, a11); a11 = SDOT4(hB1, hi, a11);
            lo = (wv.z << 4) & 0xF0F0F0F0u; hi = wv.z & 0xF0F0F0F0u;
            a02 = SDOT4(hA0, lo, a02); a02 = SDOT4(hB0, hi, a02);
            a12 = SDOT4(hA1, lo, a12); a12 = SDOT4(hB1, hi, a12);
            lo = (wv.w << 4) & 0xF0F0F0F0u; hi = wv.w & 0xF0F0F0F0u;
            a03 = SDOT4(hA0, lo, a03); a03 = SDOT4(hB0, hi, a03);
            a13 = SDOT4(hA1, lo, a13); a13 = SDOT4(hB1, hi, a13);
        }
        // tier 2: streamed octs from L2
        #pragma unroll 4
        for (int i = 0; i < 64 - JO_LDS; ++i) {
            uint4 wv = *(const uint4*)(spB + (size_t)i * 2048);
            int o = JO_LDS + i;
            uint32 hA0 = hq[0][2 * o], hB0 = hq[0][2 * o + 1];
            uint32 hA1 = hq[1][2 * o], hB1 = hq[1][2 * o + 1];
            uint32 lo, hi;
            lo = (wv.x << 4) & 0xF0F0F0F0u; hi = wv.x & 0xF0F0F0F0u;
            a00 = SDOT4(hA0, lo, a00); a00 = SDOT4(hB0, hi, a00);
            a10 = SDOT4(hA1, lo, a10); a10 = SDOT4(hB1, hi, a10);
            lo = (wv.y << 4) & 0xF0F0F0F0u; hi = wv.y & 0xF0F0F0F0u;
            a01 = SDOT4(hA0, lo, a01); a01 = SDOT4(hB0, hi, a01);
            a11 = SDOT4(hA1, lo, a11); a11 = SDOT4(hB1, hi, a11);
            lo = (wv.z << 4) & 0xF0F0F0F0u; hi = wv.z & 0xF0F0F0F0u;
            a02 = SDOT4(hA0, lo, a02); a02 = SDOT4(hB0, hi, a02);
            a12 = SDOT4(hA1, lo, a12); a12 = SDOT4(hB1, hi, a12);
            lo = (wv.w << 4) & 0xF0F0F0F0u; hi = wv.w & 0xF0F0F0F0u;
            a03 = SDOT4(hA0, lo, a03); a03 = SDOT4(hB0, hi, a03);
            a13 = SDOT4(hA1, lo, a13); a13 = SDOT4(hB1, hi, a13);
        }

        float4 p0 = make_float4(b2f(q0.x) + sc.x * (float)a00,
                                b2f(q0.y) + sc.y * (float)a01,
                                b2f(q0.z) + sc.z * (float)a02,
                                b2f(q0.w) + sc.w * (float)a03);
        float4 p1 = make_float4(b2f(q1.x) + sc.x * (float)a10,
                                b2f(q1.y) + sc.y * (float)a11,
                                b2f(q1.z) + sc.z * (float)a12,
                                b2f(q1.w) + sc.w * (float)a13);
        *(float4*)&gb[0][g4] = p0;
        *(float4*)&gb[1][g4] = p1;
        __syncthreads();

        {
            float gi = gb[0][t];
            float gf = gb[0][512 + t];
            float gg = gb[0][1024 + t];
            float go = gb[0][1536 + t];
            float iv  = 1.f / (1.f + expf(-gi));
            float fvv = 1.f / (1.f + expf(-gf));
            float gv  = tanhf(gg);
            float ov  = 1.f / (1.f + expf(-go));
            float cn = fvv * csr0 + iv * gv;
            float hn = ov * tanhf(cn);
            csr0 = cn;
            ((signed char*)hq[0])[t] = (signed char)(int)rintf(hn * 127.f);
            Lout[((size_t)(b0 + 0) * 512 + s) * 1024 + (dir << 9) + t] = f2b(hn);
        }
        {
            float gi = gb[1][t];
            float gf = gb[1][512 + t];
            float gg = gb[1][1024 + t];
            float go = gb[1][1536 + t];
            float iv  = 1.f / (1.f + expf(-gi));
            float fvv = 1.f / (1.f + expf(-gf));
            float gv  = tanhf(gg);
            float ov  = 1.f / (1.f + expf(-go));
            float cn = fvv * csr1 + iv * gv;
            float hn = ov * tanhf(cn);
            csr1 = cn;
            ((signed char*)hq[1])[t] = (signed char)(int)rintf(hn * 127.f);
            Lout[((size_t)(b0 + 1) * 512 + s) * 1024 + (dir << 9) + t] = f2b(hn);
        }
        __syncthreads();
    }
}

// --- Kernel 4: feats = Lout(bf16) @ W_out^T + b_out ------------------------
__global__ __launch_bounds__(256) void k_feats(const u16* __restrict__ Lout,
        const float* __restrict__ Wout, const float* __restrict__ bout,
        float* __restrict__ Ft) {
    __shared__ __align__(16) float Wl[12 * 1024];
    for (int i = threadIdx.x; i < 12 * 1024; i += 256) Wl[i] = Wout[i];
    __syncthreads();
    int wv = threadIdx.x >> 6, lane = threadIdx.x & 63;
    size_t row = (size_t)blockIdx.x * 4 + wv;
    const uint4* xr = (const uint4*)(Lout + row * 1024);
    float acc[12];
    #pragma unroll
    for (int tg = 0; tg < 12; ++tg) acc[tg] = 0.f;
    #pragma unroll
    for (int c = 0; c < 2; ++c) {
        int e8 = lane + (c << 6);
        uint4 xv = xr[e8];
        float x0 = flo(xv.x), x1 = fhi(xv.x);
        float x2 = flo(xv.y), x3 = fhi(xv.y);
        float x4 = flo(xv.z), x5 = fhi(xv.z);
        float x6 = flo(xv.w), x7 = fhi(xv.w);
        #pragma unroll
        for (int tg = 0; tg < 12; ++tg) {
            const float* wpt = &Wl[tg * 1024 + (e8 << 3)];
            float4 wa = *(const float4*)wpt;
            float4 wb = *(const float4*)(wpt + 4);
            acc[tg] += x0 * wa.x + x1 * wa.y + x2 * wa.z + x3 * wa.w
                     + x4 * wb.x + x5 * wb.y + x6 * wb.z + x7 * wb.w;
        }
    }
    #pragma unroll
    for (int tg = 0; tg < 12; ++tg) {
        #pragma unroll
        for (int off = 32; off > 0; off >>= 1)
            acc[tg] += __shfl_xor(acc[tg], off);
    }
    float v = 0.f;
    #pragma unroll
    for (int tg = 0; tg < 12; ++tg)
        if (lane == tg) v = acc[tg];
    if (lane < 12) Ft[row * 12 + lane] = v + bout[lane];
}

// --- Kernel 5: Viterbi per batch (1 wave). ---------------------------------
__global__ __launch_bounds__(64) void k_viterbi(const float* __restrict__ Ft,
        const float* __restrict__ trans, float* __restrict__ out) {
    int b = blockIdx.x;
    int lane = threadIdx.x;
    __shared__ unsigned char bps[512][12];
    float tr[12];
    #pragma unroll
    for (int p = 0; p < 12; ++p)
        tr[p] = (lane < 12) ? trans[lane * 12 + p] : 0.f;
    float fv = (lane == TAG_START) ? 0.f : NEGV;
    const float* fb = Ft + (size_t)b * 512 * 12;
    for (int s = 0; s < 512; ++s) {
        float m = -3.4e38f;
        int bp = 0;
        #pragma unroll
        for (int p = 0; p < 12; ++p) {
            float v = __shfl(fv, p) + tr[p];
            if (v > m) { m = v; bp = p; }
        }
        float feat = (lane < 12) ? fb[s * 12 + lane] : 0.f;
        fv = m + feat;
        if (lane < 12) bps[s][lane] = (unsigned char)bp;
    }
    float term = fv + ((lane < 12) ? trans[TAG_STOP * 12 + lane] : 0.f);
    __syncthreads();
    float best = -3.4e38f; int tag = 0;
    #pragma unroll
    for (int p = 0; p < 12; ++p) {
        float v = __shfl(term, p);
        if (v > best) { best = v; tag = p; }
    }
    if (lane == 0) {
        out[b] = best;
        int tg = tag;
        for (int s = 511; s >= 0; --s) {
            out[64 + (size_t)b * 512 + s] = (float)tg;
            tg = bps[s][tg];
        }
    }
}

extern "C" void kernel_launch(void* const* d_in, const int* in_sizes, int n_in,
                              void* d_out, int out_size, void* d_ws, size_t ws_size,
                              hipStream_t stream) {
    const int*   sent   = (const int*)  d_in[0];
    const float* emb    = (const float*)d_in[1];
    const float* W_ih_f = (const float*)d_in[2];
    const float* W_hh_f = (const float*)d_in[3];
    const float* b_f    = (const float*)d_in[4];
    const float* W_ih_b = (const float*)d_in[5];
    const float* W_hh_b = (const float*)d_in[6];
    const float* b_b    = (const float*)d_in[7];
    const float* W_out  = (const float*)d_in[8];
    const float* b_out  = (const float*)d_in[9];
    const float* trans  = (const float*)d_in[10];
    float* out = (float*)d_out;

    char* wsB = (char*)d_ws;
    size_t off = 0;
    uint32* Wn     = (uint32*)(wsB + off); off += 1048576;
    float*  s127n  = (float*) (wsB + off); off += 16384;
    u16*    Wihb   = (u16*)   (wsB + off); off += 4194304;
    float*  biascat= (float*) (wsB + off); off += 16384;
    float*  Ft     = (float*) (wsB + off); off += 1572864;
    u16*    Lout   = (u16*)   (wsB + off); off += 67108864;
    size_t fixed = off;
    u16*    Gxc    = (u16*)   (wsB + off);

    int NB = 64;
    while (NB > 2 && fixed + (size_t)NB * 4194304ull > ws_size) NB >>= 1;

    k_packw<<<4096, 256, 0, stream>>>(W_ih_f, W_ih_b, b_f, b_b, Wihb, biascat);
    k_pack <<<4096, 64, 0, stream>>>(W_hh_f, W_hh_b, Wn, s127n);
    for (int c = 0; c < 64; c += NB) {
        k_gemm<<<NB * 128, 256, 0, stream>>>(sent, emb, Wihb, biascat, Gxc, c);
        k_lstm<<<NB, 512, 0, stream>>>(Gxc, Wn, s127n, Lout, c);
    }
    k_feats  <<<8192, 256, 0, stream>>>(Lout, W_out, b_out, Ft);
    k_viterbi<<<64, 64, 0, stream>>>(Ft, trans, out);
}

// Round 10
// 5296.115 us; speedup vs baseline: 1.3056x; 1.0101x over previous
//
#include <hip/hip_runtime.h>
#include <cmath>

// Problem constants
#define NTAG    12
#define TAG_START 10
#define TAG_STOP  11
#define NEGV    (-10000.0f)

// k_lstm: of 64 j-octs, this many LDS-resident (rest streamed from L2)
#define JO_LDS 16

typedef unsigned int uint32;
typedef unsigned short u16;
typedef __attribute__((ext_vector_type(8))) short bf16x8;
typedef __attribute__((ext_vector_type(4))) float f32x4;

#if defined(__has_builtin)
# if __has_builtin(__builtin_amdgcn_sdot4)
#  define HAVE_SDOT4 1
# endif
#endif

#ifdef HAVE_SDOT4
#define SDOT4(a, b, c) __builtin_amdgcn_sdot4((int)(a), (int)(b), (c), false)
#else
__device__ inline int sdot4_sw(uint32 a, uint32 b, int c) {
    int r = c;
    r += ((int)(a << 24) >> 24) * ((int)(b << 24) >> 24);
    r += ((int)(a << 16) >> 24) * ((int)(b << 16) >> 24);
    r += ((int)(a << 8)  >> 24) * ((int)(b << 8)  >> 24);
    r += ((int)a >> 24)         * ((int)b >> 24);
    return r;
}
#define SDOT4(a, b, c) sdot4_sw((a), (b), (c))
#endif

// Accumulate one oct: weights wv (4 gate dwords), h dwords hA/hB per batch.
#define ACC_OCT(wv, hA0, hB0, hA1, hB1)                                   \
    do {                                                                  \
        uint32 lo_, hi_;                                                  \
        lo_ = ((wv).x << 4) & 0xF0F0F0F0u; hi_ = (wv).x & 0xF0F0F0F0u;    \
        a00 = SDOT4(hA0, lo_, a00); a00 = SDOT4(hB0, hi_, a00);           \
        a10 = SDOT4(hA1, lo_, a10); a10 = SDOT4(hB1, hi_, a10);           \
        lo_ = ((wv).y << 4) & 0xF0F0F0F0u; hi_ = (wv).y & 0xF0F0F0F0u;    \
        a01 = SDOT4(hA0, lo_, a01); a01 = SDOT4(hB0, hi_, a01);           \
        a11 = SDOT4(hA1, lo_, a11); a11 = SDOT4(hB1, hi_, a11);           \
        lo_ = ((wv).z << 4) & 0xF0F0F0F0u; hi_ = (wv).z & 0xF0F0F0F0u;    \
        a02 = SDOT4(hA0, lo_, a02); a02 = SDOT4(hB0, hi_, a02);           \
        a12 = SDOT4(hA1, lo_, a12); a12 = SDOT4(hB1, hi_, a12);           \
        lo_ = ((wv).w << 4) & 0xF0F0F0F0u; hi_ = (wv).w & 0xF0F0F0F0u;    \
        a03 = SDOT4(hA0, lo_, a03); a03 = SDOT4(hB0, hi_, a03);           \
        a13 = SDOT4(hA1, lo_, a13); a13 = SDOT4(hB1, hi_, a13);           \
    } while (0)

// bf16 <-> f32 helpers
__device__ inline float b2f(u16 h) {
    union { uint32 u; float f; } v; v.u = ((uint32)h) << 16; return v.f;
}
__device__ inline u16 f2b(float f) {
    union { float f; uint32 u; } v; v.f = f;
    uint32 u = v.u;
    uint32 r = (u + 0x7FFFu + ((u >> 16) & 1u)) >> 16;
    return (u16)r;
}
__device__ inline uint32 f2b2(float a, float b) {
    return (uint32)f2b(a) | ((uint32)f2b(b) << 16);
}
__device__ inline float flo(uint32 u) {
    union { uint32 u; float f; } v; v.u = u << 16; return v.f;
}
__device__ inline float fhi(uint32 u) {
    union { uint32 u; float f; } v; v.u = u & 0xFFFF0000u; return v.f;
}

// ---------------------------------------------------------------------------
// ws layout (bytes):
//   Wn      u32 [2 dir][64 oct][2048 g]   1,048,576   int4 W_hh^T (nibble-packed)
//   s127n   f32 [2][2048]                    16,384   per-row scale/(127*16)
//   Wihb    u16 [4096][512]               4,194,304   bf16 W_ih (f then b)
//   biascat f32 [4096]                       16,384   bias (f then b)
//   Ft      f32 [32768][12]               1,572,864   feats
//   Lout    bf16 [32768][1024]           67,108,864   bilstm output
//   Gx      bf16 [NB*512][4096]       NB*4,194,304    gate preacts (chunk)
// ---------------------------------------------------------------------------

// --- Kernel 0: pack W_ih + bias to bf16 concat -------------------------------
__global__ __launch_bounds__(256) void k_packw(const float* __restrict__ Wf,
        const float* __restrict__ Wb, const float* __restrict__ bf,
        const float* __restrict__ bb, u16* __restrict__ Wihb,
        float* __restrict__ biascat) {
    int g = blockIdx.x;           // 0..4095
    const float* src = (g < 2048) ? (Wf + (size_t)g * 512)
                                  : (Wb + (size_t)(g - 2048) * 512);
    for (int k = threadIdx.x; k < 512; k += 256)
        Wihb[(size_t)g * 512 + k] = f2b(src[k]);
    if (threadIdx.x == 0)
        biascat[g] = (g < 2048) ? bf[g] : bb[g - 2048];
}

// --- Kernel 1: int4 quantize+pack W_hh (unchanged r9) ------------------------
__global__ __launch_bounds__(64) void k_pack(const float* __restrict__ Wf,
                                             const float* __restrict__ Wb,
                                             uint32* __restrict__ Wn,
                                             float* __restrict__ s127n) {
    int e = blockIdx.x;                 // 0..4095
    int dir = e >> 11, g = e & 2047;
    const float* W = (dir ? Wb : Wf) + (size_t)g * 512;
    int t = threadIdx.x;                // oct index
    float w[8];
    float m = 0.f;
    #pragma unroll
    for (int i = 0; i < 8; ++i) {
        w[i] = W[t * 8 + i];
        m = fmaxf(m, fabsf(w[i]));
    }
    #pragma unroll
    for (int off = 32; off > 0; off >>= 1)
        m = fmaxf(m, __shfl_xor(m, off));
    float s = (m > 0.f) ? (m / 7.f) : 1.f;
    float inv = 1.f / s;
    uint32 d = 0;
    #pragma unroll
    for (int k = 0; k < 4; ++k) {
        uint32 qlo = (uint32)((int)rintf(w[k] * inv)) & 0xFu;
        uint32 qhi = (uint32)((int)rintf(w[4 + k] * inv)) & 0xFu;
        d |= (qlo | (qhi << 4)) << (8 * k);
    }
    Wn[((size_t)(dir * 64) + t) * 2048 + g] = d;
    if (t == 0) s127n[dir * 2048 + g] = s / (127.f * 16.f);
}

// --- Kernel 2: fused gather + input GEMM, bf16 MFMA (unchanged) -------------
__global__ __launch_bounds__(256) void k_gemm(const int* __restrict__ sent,
        const float* __restrict__ emb, const u16* __restrict__ Wihb,
        const float* __restrict__ biascat, u16* __restrict__ Gxc, int b0c) {
    __shared__ __align__(16) u16 As[128][72];
    __shared__ __align__(16) u16 Bs[128][72];
    __shared__ int ssent[128];

    int bid = blockIdx.x;
    int nb = bid & 31, mb = bid >> 5;
    int M0 = mb << 7, N0 = nb << 7;
    int t = threadIdx.x;
    int w = t >> 6, l = t & 63;
    int wr = w >> 1, wc = w & 1;

    if (t < 128) ssent[t] = sent[b0c * 512 + M0 + t];

    f32x4 zero = {0.f, 0.f, 0.f, 0.f};
    f32x4 acc[4][4];
    #pragma unroll
    for (int i = 0; i < 4; ++i)
        #pragma unroll
        for (int j = 0; j < 4; ++j) acc[i][j] = zero;

    int srow = t >> 3;
    int skc  = (t & 7) << 3;
    __syncthreads();

    for (int k0 = 0; k0 < 512; k0 += 64) {
        #pragma unroll
        for (int i = 0; i < 4; ++i) {
            int r = srow + (i << 5);
            const float* srcA = emb + (size_t)ssent[r] * 512 + k0 + skc;
            float4 f0 = *(const float4*)srcA;
            float4 f1 = *(const float4*)(srcA + 4);
            uint4 pa;
            pa.x = f2b2(f0.x, f0.y); pa.y = f2b2(f0.z, f0.w);
            pa.z = f2b2(f1.x, f1.y); pa.w = f2b2(f1.z, f1.w);
            *(uint4*)&As[r][skc] = pa;
            uint4 pb = *(const uint4*)(Wihb + (size_t)(N0 + r) * 512 + k0 + skc);
            *(uint4*)&Bs[r][skc] = pb;
        }
        __syncthreads();
        int lrow = l & 15, lk = (l >> 4) << 3;
        #pragma unroll
        for (int kk = 0; kk < 64; kk += 32) {
            bf16x8 af[4], bfr[4];
            #pragma unroll
            for (int i = 0; i < 4; ++i)
                af[i] = *(const bf16x8*)&As[(wr << 6) + (i << 4) + lrow][kk + lk];
            #pragma unroll
            for (int j = 0; j < 4; ++j)
                bfr[j] = *(const bf16x8*)&Bs[(wc << 6) + (j << 4) + lrow][kk + lk];
            #pragma unroll
            for (int i = 0; i < 4; ++i)
                #pragma unroll
                for (int j = 0; j < 4; ++j)
                    acc[i][j] = __builtin_amdgcn_mfma_f32_16x16x32_bf16(
                        af[i], bfr[j], acc[i][j], 0, 0, 0);
        }
        __syncthreads();
    }

    int lrow = l & 15, lq = l >> 4;
    #pragma unroll
    for (int j = 0; j < 4; ++j) {
        int col = N0 + (wc << 6) + (j << 4) + lrow;
        float bv = biascat[col];
        #pragma unroll
        for (int i = 0; i < 4; ++i) {
            int rbase = M0 + (wr << 6) + (i << 4) + (lq << 2);
            #pragma unroll
            for (int r = 0; r < 4; ++r)
                Gxc[(size_t)(rbase + r) * 4096 + col] = f2b(acc[i][j][r] + bv);
        }
    }
}

// --- Kernel 3: BiLSTM recurrence, int4 weights, b128 h-broadcast -------------
// One block = (2 batches, 1 dir). Octs 0..JO_LDS-1 LDS-resident, rest streamed.
// h read as uint4 (covers 2 octs): 64 ds_read_b128/step instead of 256 b32.
__global__ __launch_bounds__(512, 2) void k_lstm(const u16* __restrict__ Gxc,
        const uint32* __restrict__ Wn, const float* __restrict__ s127n,
        u16* __restrict__ Lout, int b0c) {
    int dir, slot;
    if (gridDim.x >= 8) {
        int xid = blockIdx.x & 7, q = blockIdx.x >> 3;
        dir  = xid >> 2;
        slot = (xid & 3) | (q << 2);
    } else {
        dir  = blockIdx.x & 1;
        slot = blockIdx.x >> 1;
    }
    int b0  = b0c + (slot << 1);
    int lb0 = slot << 1;

    __shared__ __align__(16) uint32 wlds[JO_LDS][2048]; // 128 KB int4 weights
    __shared__ __align__(16) uint32 hq[2][128];         // i8-packed h
    __shared__ __align__(16) float  gb[2][2048];        // gate preacts

    int t = threadIdx.x;
    if (t < 256) hq[t >> 7][t & 127] = 0u;
    float csr0 = 0.f, csr1 = 0.f;

    const uint32* wsrc = Wn + (size_t)dir * (64 * 2048);
    {   // preload LDS tier
        const uint4* src = (const uint4*)wsrc;
        uint4* dst = (uint4*)wlds;
        #pragma unroll
        for (int i = 0; i < JO_LDS; ++i)
            dst[t + i * 512] = src[t + i * 512];
    }
    int g4 = t << 2;
    float4 sc = *(const float4*)(s127n + dir * 2048 + g4);
    const u16* gxb0 = Gxc + (size_t)lb0 * 512 * 4096 + (dir << 11) + g4;
    const u16* gxb1 = gxb0 + (size_t)512 * 4096;
    const uint32* spB = wsrc + (size_t)JO_LDS * 2048 + g4;
    const uint4* hq4_0 = (const uint4*)hq[0];
    const uint4* hq4_1 = (const uint4*)hq[1];
    __syncthreads();

    for (int si = 0; si < 512; ++si) {
        int s = dir ? (511 - si) : si;
        ushort4 q0 = *(const ushort4*)(gxb0 + (size_t)s * 4096);
        ushort4 q1 = *(const ushort4*)(gxb1 + (size_t)s * 4096);

        int a00 = 0, a01 = 0, a02 = 0, a03 = 0;
        int a10 = 0, a11 = 0, a12 = 0, a13 = 0;

        // tier 1: LDS-resident oct pairs (p covers octs 2p, 2p+1)
        #pragma unroll
        for (int p = 0; p < JO_LDS / 2; ++p) {
            uint4 w0 = *(const uint4*)&wlds[2 * p][g4];
            uint4 w1 = *(const uint4*)&wlds[2 * p + 1][g4];
            uint4 h0 = hq4_0[p];
            uint4 h1 = hq4_1[p];
            ACC_OCT(w0, h0.x, h0.y, h1.x, h1.y);
            ACC_OCT(w1, h0.z, h0.w, h1.z, h1.w);
        }
        // tier 2: streamed oct pairs from L2
        #pragma unroll 2
        for (int p = 0; p < (64 - JO_LDS) / 2; ++p) {
            uint4 w0 = *(const uint4*)(spB + (size_t)(2 * p) * 2048);
            uint4 w1 = *(const uint4*)(spB + (size_t)(2 * p + 1) * 2048);
            uint4 h0 = hq4_0[JO_LDS / 2 + p];
            uint4 h1 = hq4_1[JO_LDS / 2 + p];
            ACC_OCT(w0, h0.x, h0.y, h1.x, h1.y);
            ACC_OCT(w1, h0.z, h0.w, h1.z, h1.w);
        }

        float4 p0 = make_float4(b2f(q0.x) + sc.x * (float)a00,
                                b2f(q0.y) + sc.y * (float)a01,
                                b2f(q0.z) + sc.z * (float)a02,
                                b2f(q0.w) + sc.w * (float)a03);
        float4 p1 = make_float4(b2f(q1.x) + sc.x * (float)a10,
                                b2f(q1.y) + sc.y * (float)a11,
                                b2f(q1.z) + sc.z * (float)a12,
                                b2f(q1.w) + sc.w * (float)a13);
        *(float4*)&gb[0][g4] = p0;
        *(float4*)&gb[1][g4] = p1;
        __syncthreads();

        {
            float gi = gb[0][t];
            float gf = gb[0][512 + t];
            float gg = gb[0][1024 + t];
            float go = gb[0][1536 + t];
            float iv  = 1.f / (1.f + expf(-gi));
            float fvv = 1.f / (1.f + expf(-gf));
            float gv  = tanhf(gg);
            float ov  = 1.f / (1.f + expf(-go));
            float cn = fvv * csr0 + iv * gv;
            float hn = ov * tanhf(cn);
            csr0 = cn;
            ((signed char*)hq[0])[t] = (signed char)(int)rintf(hn * 127.f);
            Lout[((size_t)(b0 + 0) * 512 + s) * 1024 + (dir << 9) + t] = f2b(hn);
        }
        {
            float gi = gb[1][t];
            float gf = gb[1][512 + t];
            float gg = gb[1][1024 + t];
            float go = gb[1][1536 + t];
            float iv  = 1.f / (1.f + expf(-gi));
            float fvv = 1.f / (1.f + expf(-gf));
            float gv  = tanhf(gg);
            float ov  = 1.f / (1.f + expf(-go));
            float cn = fvv * csr1 + iv * gv;
            float hn = ov * tanhf(cn);
            csr1 = cn;
            ((signed char*)hq[1])[t] = (signed char)(int)rintf(hn * 127.f);
            Lout[((size_t)(b0 + 1) * 512 + s) * 1024 + (dir << 9) + t] = f2b(hn);
        }
        __syncthreads();
    }
}

// --- Kernel 4: feats = Lout(bf16) @ W_out^T + b_out ------------------------
__global__ __launch_bounds__(256) void k_feats(const u16* __restrict__ Lout,
        const float* __restrict__ Wout, const float* __restrict__ bout,
        float* __restrict__ Ft) {
    __shared__ __align__(16) float Wl[12 * 1024];
    for (int i = threadIdx.x; i < 12 * 1024; i += 256) Wl[i] = Wout[i];
    __syncthreads();
    int wv = threadIdx.x >> 6, lane = threadIdx.x & 63;
    size_t row = (size_t)blockIdx.x * 4 + wv;
    const uint4* xr = (const uint4*)(Lout + row * 1024);
    float acc[12];
    #pragma unroll
    for (int tg = 0; tg < 12; ++tg) acc[tg] = 0.f;
    #pragma unroll
    for (int c = 0; c < 2; ++c) {
        int e8 = lane + (c << 6);
        uint4 xv = xr[e8];
        float x0 = flo(xv.x), x1 = fhi(xv.x);
        float x2 = flo(xv.y), x3 = fhi(xv.y);
        float x4 = flo(xv.z), x5 = fhi(xv.z);
        float x6 = flo(xv.w), x7 = fhi(xv.w);
        #pragma unroll
        for (int tg = 0; tg < 12; ++tg) {
            const float* wpt = &Wl[tg * 1024 + (e8 << 3)];
            float4 wa = *(const float4*)wpt;
            float4 wb = *(const float4*)(wpt + 4);
            acc[tg] += x0 * wa.x + x1 * wa.y + x2 * wa.z + x3 * wa.w
                     + x4 * wb.x + x5 * wb.y + x6 * wb.z + x7 * wb.w;
        }
    }
    #pragma unroll
    for (int tg = 0; tg < 12; ++tg) {
        #pragma unroll
        for (int off = 32; off > 0; off >>= 1)
            acc[tg] += __shfl_xor(acc[tg], off);
    }
    float v = 0.f;
    #pragma unroll
    for (int tg = 0; tg < 12; ++tg)
        if (lane == tg) v = acc[tg];
    if (lane < 12) Ft[row * 12 + lane] = v + bout[lane];
}

// --- Kernel 5: Viterbi per batch (1 wave). ---------------------------------
__global__ __launch_bounds__(64) void k_viterbi(const float* __restrict__ Ft,
        const float* __restrict__ trans, float* __restrict__ out) {
    int b = blockIdx.x;
    int lane = threadIdx.x;
    __shared__ unsigned char bps[512][12];
    float tr[12];
    #pragma unroll
    for (int p = 0; p < 12; ++p)
        tr[p] = (lane < 12) ? trans[lane * 12 + p] : 0.f;
    float fv = (lane == TAG_START) ? 0.f : NEGV;
    const float* fb = Ft + (size_t)b * 512 * 12;
    for (int s = 0; s < 512; ++s) {
        float m = -3.4e38f;
        int bp = 0;
        #pragma unroll
        for (int p = 0; p < 12; ++p) {
            float v = __shfl(fv, p) + tr[p];
            if (v > m) { m = v; bp = p; }
        }
        float feat = (lane < 12) ? fb[s * 12 + lane] : 0.f;
        fv = m + feat;
        if (lane < 12) bps[s][lane] = (unsigned char)bp;
    }
    float term = fv + ((lane < 12) ? trans[TAG_STOP * 12 + lane] : 0.f);
    __syncthreads();
    float best = -3.4e38f; int tag = 0;
    #pragma unroll
    for (int p = 0; p < 12; ++p) {
        float v = __shfl(term, p);
        if (v > best) { best = v; tag = p; }
    }
    if (lane == 0) {
        out[b] = best;
        int tg = tag;
        for (int s = 511; s >= 0; --s) {
            out[64 + (size_t)b * 512 + s] = (float)tg;
            tg = bps[s][tg];
        }
    }
}

extern "C" void kernel_launch(void* const* d_in, const int* in_sizes, int n_in,
                              void* d_out, int out_size, void* d_ws, size_t ws_size,
                              hipStream_t stream) {
    const int*   sent   = (const int*)  d_in[0];
    const float* emb    = (const float*)d_in[1];
    const float* W_ih_f = (const float*)d_in[2];
    const float* W_hh_f = (const float*)d_in[3];
    const float* b_f    = (const float*)d_in[4];
    const float* W_ih_b = (const float*)d_in[5];
    const float* W_hh_b = (const float*)d_in[6];
    const float* b_b    = (const float*)d_in[7];
    const float* W_out  = (const float*)d_in[8];
    const float* b_out  = (const float*)d_in[9];
    const float* trans  = (const float*)d_in[10];
    float* out = (float*)d_out;

    char* wsB = (char*)d_ws;
    size_t off = 0;
    uint32* Wn     = (uint32*)(wsB + off); off += 1048576;
    float*  s127n  = (float*) (wsB + off); off += 16384;
    u16*    Wihb   = (u16*)   (wsB + off); off += 4194304;
    float*  biascat= (float*) (wsB + off); off += 16384;
    float*  Ft     = (float*) (wsB + off); off += 1572864;
    u16*    Lout   = (u16*)   (wsB + off); off += 67108864;
    size_t fixed = off;
    u16*    Gxc    = (u16*)   (wsB + off);

    int NB = 64;
    while (NB > 2 && fixed + (size_t)NB * 4194304ull > ws_size) NB >>= 1;

    k_packw<<<4096, 256, 0, stream>>>(W_ih_f, W_ih_b, b_f, b_b, Wihb, biascat);
    k_pack <<<4096, 64, 0, stream>>>(W_hh_f, W_hh_b, Wn, s127n);
    for (int c = 0; c < 64; c += NB) {
        k_gemm<<<NB * 128, 256, 0, stream>>>(sent, emb, Wihb, biascat, Gxc, c);
        k_lstm<<<NB, 512, 0, stream>>>(Gxc, Wn, s127n, Lout, c);
    }
    k_feats  <<<8192, 256, 0, stream>>>(Lout, W_out, b_out, Ft);
    k_viterbi<<<64, 64, 0, stream>>>(Ft, trans, out);
}

// Round 11
// 2971.300 us; speedup vs baseline: 2.3272x; 1.7824x over previous
//
#include <hip/hip_runtime.h>
#include <cmath>

// Problem constants
#define NTAG    12
#define TAG_START 10
#define TAG_STOP  11
#define NEGV    (-10000.0f)

// k_lstm: of 64 j-octs, this many LDS-resident (rest streamed from L2)
#define JO_LDS 16

typedef unsigned int uint32;
typedef unsigned short u16;
typedef __attribute__((ext_vector_type(8))) short bf16x8;
typedef __attribute__((ext_vector_type(4))) float f32x4;

#if defined(__has_builtin)
# if __has_builtin(__builtin_amdgcn_sdot4)
#  define HAVE_SDOT4 1
# endif
# if __has_builtin(__builtin_amdgcn_sdot8)
#  define HAVE_SDOT8 1
# endif
#endif

#ifdef HAVE_SDOT4
#define SDOT4(a, b, c) __builtin_amdgcn_sdot4((int)(a), (int)(b), (c), false)
#else
__device__ inline int sdot4_sw(uint32 a, uint32 b, int c) {
    int r = c;
    r += ((int)(a << 24) >> 24) * ((int)(b << 24) >> 24);
    r += ((int)(a << 16) >> 24) * ((int)(b << 16) >> 24);
    r += ((int)(a << 8)  >> 24) * ((int)(b << 8)  >> 24);
    r += ((int)a >> 24)         * ((int)b >> 24);
    return r;
}
#define SDOT4(a, b, c) sdot4_sw((a), (b), (c))
#endif

#ifdef HAVE_SDOT8
#define SDOT8(a, b, c) __builtin_amdgcn_sdot8((int)(a), (int)(b), (c), false)
#endif

// bf16 <-> f32 helpers
__device__ inline float b2f(u16 h) {
    union { uint32 u; float f; } v; v.u = ((uint32)h) << 16; return v.f;
}
__device__ inline u16 f2b(float f) {
    union { float f; uint32 u; } v; v.f = f;
    uint32 u = v.u;
    uint32 r = (u + 0x7FFFu + ((u >> 16) & 1u)) >> 16;
    return (u16)r;
}
__device__ inline uint32 f2b2(float a, float b) {
    return (uint32)f2b(a) | ((uint32)f2b(b) << 16);
}
__device__ inline float flo(uint32 u) {
    union { uint32 u; float f; } v; v.u = u << 16; return v.f;
}
__device__ inline float fhi(uint32 u) {
    union { uint32 u; float f; } v; v.u = u & 0xFFFF0000u; return v.f;
}

// ---------------------------------------------------------------------------
// ws layout (bytes) — same for both paths:
//   Wn      u32 [2 dir][64 oct][2048 g]   1,048,576   int4 W_hh^T
//   sW      f32 [2][2048]                    16,384   per-row combined scale
//   Wihb    u16 [4096][512]               4,194,304   bf16 W_ih (f then b)
//   biascat f32 [4096]                       16,384   bias (f then b)
//   Ft      f32 [32768][12]               1,572,864   feats
//   Lout    bf16 [32768][1024]           67,108,864   bilstm output
//   Gx      bf16 [NB*512][4096]       NB*4,194,304    gate preacts (chunk)
// ---------------------------------------------------------------------------

// --- Kernel 0: pack W_ih + bias to bf16 concat -------------------------------
__global__ __launch_bounds__(256) void k_packw(const float* __restrict__ Wf,
        const float* __restrict__ Wb, const float* __restrict__ bf,
        const float* __restrict__ bb, u16* __restrict__ Wihb,
        float* __restrict__ biascat) {
    int g = blockIdx.x;           // 0..4095
    const float* src = (g < 2048) ? (Wf + (size_t)g * 512)
                                  : (Wb + (size_t)(g - 2048) * 512);
    for (int k = threadIdx.x; k < 512; k += 256)
        Wihb[(size_t)g * 512 + k] = f2b(src[k]);
    if (threadIdx.x == 0)
        biascat[g] = (g < 2048) ? bf[g] : bb[g - 2048];
}

// --- Kernel 2: fused gather + input GEMM, bf16 MFMA (unchanged) -------------
__global__ __launch_bounds__(256) void k_gemm(const int* __restrict__ sent,
        const float* __restrict__ emb, const u16* __restrict__ Wihb,
        const float* __restrict__ biascat, u16* __restrict__ Gxc, int b0c) {
    __shared__ __align__(16) u16 As[128][72];
    __shared__ __align__(16) u16 Bs[128][72];
    __shared__ int ssent[128];

    int bid = blockIdx.x;
    int nb = bid & 31, mb = bid >> 5;
    int M0 = mb << 7, N0 = nb << 7;
    int t = threadIdx.x;
    int w = t >> 6, l = t & 63;
    int wr = w >> 1, wc = w & 1;

    if (t < 128) ssent[t] = sent[b0c * 512 + M0 + t];

    f32x4 zero = {0.f, 0.f, 0.f, 0.f};
    f32x4 acc[4][4];
    #pragma unroll
    for (int i = 0; i < 4; ++i)
        #pragma unroll
        for (int j = 0; j < 4; ++j) acc[i][j] = zero;

    int srow = t >> 3;
    int skc  = (t & 7) << 3;
    __syncthreads();

    for (int k0 = 0; k0 < 512; k0 += 64) {
        #pragma unroll
        for (int i = 0; i < 4; ++i) {
            int r = srow + (i << 5);
            const float* srcA = emb + (size_t)ssent[r] * 512 + k0 + skc;
            float4 f0 = *(const float4*)srcA;
            float4 f1 = *(const float4*)(srcA + 4);
            uint4 pa;
            pa.x = f2b2(f0.x, f0.y); pa.y = f2b2(f0.z, f0.w);
            pa.z = f2b2(f1.x, f1.y); pa.w = f2b2(f1.z, f1.w);
            *(uint4*)&As[r][skc] = pa;
            uint4 pb = *(const uint4*)(Wihb + (size_t)(N0 + r) * 512 + k0 + skc);
            *(uint4*)&Bs[r][skc] = pb;
        }
        __syncthreads();
        int lrow = l & 15, lk = (l >> 4) << 3;
        #pragma unroll
        for (int kk = 0; kk < 64; kk += 32) {
            bf16x8 af[4], bfr[4];
            #pragma unroll
            for (int i = 0; i < 4; ++i)
                af[i] = *(const bf16x8*)&As[(wr << 6) + (i << 4) + lrow][kk + lk];
            #pragma unroll
            for (int j = 0; j < 4; ++j)
                bfr[j] = *(const bf16x8*)&Bs[(wc << 6) + (j << 4) + lrow][kk + lk];
            #pragma unroll
            for (int i = 0; i < 4; ++i)
                #pragma unroll
                for (int j = 0; j < 4; ++j)
                    acc[i][j] = __builtin_amdgcn_mfma_f32_16x16x32_bf16(
                        af[i], bfr[j], acc[i][j], 0, 0, 0);
        }
        __syncthreads();
    }

    int lrow = l & 15, lq = l >> 4;
    #pragma unroll
    for (int j = 0; j < 4; ++j) {
        int col = N0 + (wc << 6) + (j << 4) + lrow;
        float bv = biascat[col];
        #pragma unroll
        for (int i = 0; i < 4; ++i) {
            int rbase = M0 + (wr << 6) + (i << 4) + (lq << 2);
            #pragma unroll
            for (int r = 0; r < 4; ++r)
                Gxc[(size_t)(rbase + r) * 4096 + col] = f2b(acc[i][j][r] + bv);
        }
    }
}

#ifdef HAVE_SDOT8
// ===========================================================================
// dot8 path: weights int4 as 8 nibbles/dword, h int4 nibble-packed.
// ===========================================================================

// --- Kernel 1: pack W_hh as dot8 nibbles. One wave per (dir, gate row). -----
// Wn[(dir*64+o)*2048+g]: nibble i = rint(W[g][8o+i] * 7 / maxrow).
// sW[dir*2048+g] = maxrow/49   (= w-scale * h-scale(1/7))
__global__ __launch_bounds__(64) void k_pack(const float* __restrict__ Wf,
                                             const float* __restrict__ Wb,
                                             uint32* __restrict__ Wn,
                                             float* __restrict__ sW) {
    int e = blockIdx.x;                 // 0..4095
    int dir = e >> 11, g = e & 2047;
    const float* W = (dir ? Wb : Wf) + (size_t)g * 512;
    int t = threadIdx.x;                // oct index
    float w[8];
    float m = 0.f;
    #pragma unroll
    for (int i = 0; i < 8; ++i) {
        w[i] = W[t * 8 + i];
        m = fmaxf(m, fabsf(w[i]));
    }
    #pragma unroll
    for (int off = 32; off > 0; off >>= 1)
        m = fmaxf(m, __shfl_xor(m, off));
    float s = (m > 0.f) ? (m / 7.f) : 1.f;
    float inv = 1.f / s;
    uint32 d = 0;
    #pragma unroll
    for (int k = 0; k < 8; ++k) {
        uint32 q = (uint32)((int)rintf(w[k] * inv)) & 0xFu;
        d |= q << (4 * k);
    }
    Wn[((size_t)(dir * 64) + t) * 2048 + g] = d;
    if (t == 0) sW[dir * 2048 + g] = s / 7.f;
}

// 8 dot8 per oct: h dword (8 units) x 4 gate weight dwords x 2 batches
#define D8_OCT(h0d, h1d, wv)                                              \
    do {                                                                  \
        a00 = SDOT8(h0d, (wv).x, a00); a01 = SDOT8(h0d, (wv).y, a01);     \
        a02 = SDOT8(h0d, (wv).z, a02); a03 = SDOT8(h0d, (wv).w, a03);     \
        a10 = SDOT8(h1d, (wv).x, a10); a11 = SDOT8(h1d, (wv).y, a11);     \
        a12 = SDOT8(h1d, (wv).z, a12); a13 = SDOT8(h1d, (wv).w, a13);     \
    } while (0)

// --- Kernel 3: BiLSTM recurrence, int4 x int4 dot8 --------------------------
__global__ __launch_bounds__(512, 2) void k_lstm(const u16* __restrict__ Gxc,
        const uint32* __restrict__ Wn, const float* __restrict__ sW,
        u16* __restrict__ Lout, int b0c) {
    int dir, slot;
    if (gridDim.x >= 8) {
        int xid = blockIdx.x & 7, q = blockIdx.x >> 3;
        dir  = xid >> 2;
        slot = (xid & 3) | (q << 2);
    } else {
        dir  = blockIdx.x & 1;
        slot = blockIdx.x >> 1;
    }
    int b0  = b0c + (slot << 1);
    int lb0 = slot << 1;

    __shared__ __align__(16) uint32 wlds[JO_LDS][2048]; // 128 KB weights (octs 0..15)
    __shared__ __align__(16) uint32 hq4[2][64];         // i4-packed h (8 units/dword)
    __shared__ __align__(16) float  gb[2][2048];        // gate preacts

    int t = threadIdx.x;
    if (t < 128) hq4[t >> 6][t & 63] = 0u;
    float csr0 = 0.f, csr1 = 0.f;

    const uint32* wsrc = Wn + (size_t)dir * (64 * 2048);
    {   // preload LDS tier
        const uint4* src = (const uint4*)wsrc;
        uint4* dst = (uint4*)wlds;
        #pragma unroll
        for (int i = 0; i < JO_LDS; ++i)
            dst[t + i * 512] = src[t + i * 512];
    }
    int g4 = t << 2;
    float4 sc = *(const float4*)(sW + dir * 2048 + g4);
    const u16* gxb0 = Gxc + (size_t)lb0 * 512 * 4096 + (dir << 11) + g4;
    const u16* gxb1 = gxb0 + (size_t)512 * 4096;
    const uint32* spB = wsrc + (size_t)JO_LDS * 2048 + g4;
    const uint4* hg0 = (const uint4*)hq4[0];   // group p = octs 4p..4p+3
    const uint4* hg1 = (const uint4*)hq4[1];
    int sh = (t & 7) << 2;                     // nibble shift for h packing
    __syncthreads();

    for (int si = 0; si < 512; ++si) {
        int s = dir ? (511 - si) : si;
        ushort4 q0 = *(const ushort4*)(gxb0 + (size_t)s * 4096);
        ushort4 q1 = *(const ushort4*)(gxb1 + (size_t)s * 4096);

        int a00 = 0, a01 = 0, a02 = 0, a03 = 0;
        int a10 = 0, a11 = 0, a12 = 0, a13 = 0;

        // tier 1: LDS-resident octs 0..15 (4 h-groups of 4 octs)
        #pragma unroll
        for (int p = 0; p < JO_LDS / 4; ++p) {
            uint4 h0 = hg0[p];
            uint4 h1 = hg1[p];
            uint4 w0 = *(const uint4*)&wlds[4 * p + 0][g4];
            uint4 w1 = *(const uint4*)&wlds[4 * p + 1][g4];
            uint4 w2 = *(const uint4*)&wlds[4 * p + 2][g4];
            uint4 w3 = *(const uint4*)&wlds[4 * p + 3][g4];
            D8_OCT(h0.x, h1.x, w0);
            D8_OCT(h0.y, h1.y, w1);
            D8_OCT(h0.z, h1.z, w2);
            D8_OCT(h0.w, h1.w, w3);
        }
        // tier 2: streamed octs 16..63 (12 h-groups of 4 octs)
        #pragma unroll 4
        for (int p = 0; p < (64 - JO_LDS) / 4; ++p) {
            uint4 h0 = hg0[JO_LDS / 4 + p];
            uint4 h1 = hg1[JO_LDS / 4 + p];
            uint4 w0 = *(const uint4*)(spB + (size_t)(4 * p + 0) * 2048);
            uint4 w1 = *(const uint4*)(spB + (size_t)(4 * p + 1) * 2048);
            uint4 w2 = *(const uint4*)(spB + (size_t)(4 * p + 2) * 2048);
            uint4 w3 = *(const uint4*)(spB + (size_t)(4 * p + 3) * 2048);
            D8_OCT(h0.x, h1.x, w0);
            D8_OCT(h0.y, h1.y, w1);
            D8_OCT(h0.z, h1.z, w2);
            D8_OCT(h0.w, h1.w, w3);
        }

        float4 p0 = make_float4(b2f(q0.x) + sc.x * (float)a00,
                                b2f(q0.y) + sc.y * (float)a01,
                                b2f(q0.z) + sc.z * (float)a02,
                                b2f(q0.w) + sc.w * (float)a03);
        float4 p1 = make_float4(b2f(q1.x) + sc.x * (float)a10,
                                b2f(q1.y) + sc.y * (float)a11,
                                b2f(q1.z) + sc.z * (float)a12,
                                b2f(q1.w) + sc.w * (float)a13);
        *(float4*)&gb[0][g4] = p0;
        *(float4*)&gb[1][g4] = p1;
        __syncthreads();

        // activation: thread t = unit t, both batches; c in registers.
        // h quantized to int4 (scale 1/7) and nibble-packed via 8-lane OR.
        {
            float gi = gb[0][t];
            float gf = gb[0][512 + t];
            float gg = gb[0][1024 + t];
            float go = gb[0][1536 + t];
            float iv  = 1.f / (1.f + expf(-gi));
            float fvv = 1.f / (1.f + expf(-gf));
            float gv  = tanhf(gg);
            float ov  = 1.f / (1.f + expf(-go));
            float cn = fvv * csr0 + iv * gv;
            float hn = ov * tanhf(cn);
            csr0 = cn;
            uint32 v = (((uint32)(int)rintf(hn * 7.f)) & 0xFu) << sh;
            v |= __shfl_xor(v, 1); v |= __shfl_xor(v, 2); v |= __shfl_xor(v, 4);
            if ((t & 7) == 0) hq4[0][t >> 3] = v;
            Lout[((size_t)(b0 + 0) * 512 + s) * 1024 + (dir << 9) + t] = f2b(hn);
        }
        {
            float gi = gb[1][t];
            float gf = gb[1][512 + t];
            float gg = gb[1][1024 + t];
            float go = gb[1][1536 + t];
            float iv  = 1.f / (1.f + expf(-gi));
            float fvv = 1.f / (1.f + expf(-gf));
            float gv  = tanhf(gg);
            float ov  = 1.f / (1.f + expf(-go));
            float cn = fvv * csr1 + iv * gv;
            float hn = ov * tanhf(cn);
            csr1 = cn;
            uint32 v = (((uint32)(int)rintf(hn * 7.f)) & 0xFu) << sh;
            v |= __shfl_xor(v, 1); v |= __shfl_xor(v, 2); v |= __shfl_xor(v, 4);
            if ((t & 7) == 0) hq4[1][t >> 3] = v;
            Lout[((size_t)(b0 + 1) * 512 + s) * 1024 + (dir << 9) + t] = f2b(hn);
        }
        __syncthreads();
    }
}

#else
// ===========================================================================
// Fallback (no sdot8): round-10 int4+sdot4 path, verbatim.
// ===========================================================================

__global__ __launch_bounds__(64) void k_pack(const float* __restrict__ Wf,
                                             const float* __restrict__ Wb,
                                             uint32* __restrict__ Wn,
                                             float* __restrict__ sW) {
    int e = blockIdx.x;
    int dir = e >> 11, g = e & 2047;
    const float* W = (dir ? Wb : Wf) + (size_t)g * 512;
    int t = threadIdx.x;
    float w[8];
    float m = 0.f;
    #pragma unroll
    for (int i = 0; i < 8; ++i) {
        w[i] = W[t * 8 + i];
        m = fmaxf(m, fabsf(w[i]));
    }
    #pragma unroll
    for (int off = 32; off > 0; off >>= 1)
        m = fmaxf(m, __shfl_xor(m, off));
    float s = (m > 0.f) ? (m / 7.f) : 1.f;
    float inv = 1.f / s;
    uint32 d = 0;
    #pragma unroll
    for (int k = 0; k < 4; ++k) {
        uint32 qlo = (uint32)((int)rintf(w[k] * inv)) & 0xFu;
        uint32 qhi = (uint32)((int)rintf(w[4 + k] * inv)) & 0xFu;
        d |= (qlo | (qhi << 4)) << (8 * k);
    }
    Wn[((size_t)(dir * 64) + t) * 2048 + g] = d;
    if (t == 0) sW[dir * 2048 + g] = s / (127.f * 16.f);
}

#define ACC_OCT(wv, hA0, hB0, hA1, hB1)                                   \
    do {                                                                  \
        uint32 lo_, hi_;                                                  \
        lo_ = ((wv).x << 4) & 0xF0F0F0F0u; hi_ = (wv).x & 0xF0F0F0F0u;    \
        a00 = SDOT4(hA0, lo_, a00); a00 = SDOT4(hB0, hi_, a00);           \
        a10 = SDOT4(hA1, lo_, a10); a10 = SDOT4(hB1, hi_, a10);           \
        lo_ = ((wv).y << 4) & 0xF0F0F0F0u; hi_ = (wv).y & 0xF0F0F0F0u;    \
        a01 = SDOT4(hA0, lo_, a01); a01 = SDOT4(hB0, hi_, a01);           \
        a11 = SDOT4(hA1, lo_, a11); a11 = SDOT4(hB1, hi_, a11);           \
        lo_ = ((wv).z << 4) & 0xF0F0F0F0u; hi_ = (wv).z & 0xF0F0F0F0u;    \
        a02 = SDOT4(hA0, lo_, a02); a02 = SDOT4(hB0, hi_, a02);           \
        a12 = SDOT4(hA1, lo_, a12); a12 = SDOT4(hB1, hi_, a12);           \
        lo_ = ((wv).w << 4) & 0xF0F0F0F0u; hi_ = (wv).w & 0xF0F0F0F0u;    \
        a03 = SDOT4(hA0, lo_, a03); a03 = SDOT4(hB0, hi_, a03);           \
        a13 = SDOT4(hA1, lo_, a13); a13 = SDOT4(hB1, hi_, a13);           \
    } while (0)

__global__ __launch_bounds__(512, 2) void k_lstm(const u16* __restrict__ Gxc,
        const uint32* __restrict__ Wn, const float* __restrict__ sW,
        u16* __restrict__ Lout, int b0c) {
    int dir, slot;
    if (gridDim.x >= 8) {
        int xid = blockIdx.x & 7, q = blockIdx.x >> 3;
        dir  = xid >> 2;
        slot = (xid & 3) | (q << 2);
    } else {
        dir  = blockIdx.x & 1;
        slot = blockIdx.x >> 1;
    }
    int b0  = b0c + (slot << 1);
    int lb0 = slot << 1;

    __shared__ __align__(16) uint32 wlds[JO_LDS][2048];
    __shared__ __align__(16) uint32 hq[2][128];
    __shared__ __align__(16) float  gb[2][2048];

    int t = threadIdx.x;
    if (t < 256) hq[t >> 7][t & 127] = 0u;
    float csr0 = 0.f, csr1 = 0.f;

    const uint32* wsrc = Wn + (size_t)dir * (64 * 2048);
    {
        const uint4* src = (const uint4*)wsrc;
        uint4* dst = (uint4*)wlds;
        #pragma unroll
        for (int i = 0; i < JO_LDS; ++i)
            dst[t + i * 512] = src[t + i * 512];
    }
    int g4 = t << 2;
    float4 sc = *(const float4*)(sW + dir * 2048 + g4);
    const u16* gxb0 = Gxc + (size_t)lb0 * 512 * 4096 + (dir << 11) + g4;
    const u16* gxb1 = gxb0 + (size_t)512 * 4096;
    const uint32* spB = wsrc + (size_t)JO_LDS * 2048 + g4;
    const uint4* hq4_0 = (const uint4*)hq[0];
    const uint4* hq4_1 = (const uint4*)hq[1];
    __syncthreads();

    for (int si = 0; si < 512; ++si) {
        int s = dir ? (511 - si) : si;
        ushort4 q0 = *(const ushort4*)(gxb0 + (size_t)s * 4096);
        ushort4 q1 = *(const ushort4*)(gxb1 + (size_t)s * 4096);

        int a00 = 0, a01 = 0, a02 = 0, a03 = 0;
        int a10 = 0, a11 = 0, a12 = 0, a13 = 0;

        #pragma unroll
        for (int p = 0; p < JO_LDS / 2; ++p) {
            uint4 w0 = *(const uint4*)&wlds[2 * p][g4];
            uint4 w1 = *(const uint4*)&wlds[2 * p + 1][g4];
            uint4 h0 = hq4_0[p];
            uint4 h1 = hq4_1[p];
            ACC_OCT(w0, h0.x, h0.y, h1.x, h1.y);
            ACC_OCT(w1, h0.z, h0.w, h1.z, h1.w);
        }
        #pragma unroll 2
        for (int p = 0; p < (64 - JO_LDS) / 2; ++p) {
            uint4 w0 = *(const uint4*)(spB + (size_t)(2 * p) * 2048);
            uint4 w1 = *(const uint4*)(spB + (size_t)(2 * p + 1) * 2048);
            uint4 h0 = hq4_0[JO_LDS / 2 + p];
            uint4 h1 = hq4_1[JO_LDS / 2 + p];
            ACC_OCT(w0, h0.x, h0.y, h1.x, h1.y);
            ACC_OCT(w1, h0.z, h0.w, h1.z, h1.w);
        }

        float4 p0 = make_float4(b2f(q0.x) + sc.x * (float)a00,
                                b2f(q0.y) + sc.y * (float)a01,
                                b2f(q0.z) + sc.z * (float)a02,
                                b2f(q0.w) + sc.w * (float)a03);
        float4 p1 = make_float4(b2f(q1.x) + sc.x * (float)a10,
                                b2f(q1.y) + sc.y * (float)a11,
                                b2f(q1.z) + sc.z * (float)a12,
                                b2f(q1.w) + sc.w * (float)a13);
        *(float4*)&gb[0][g4] = p0;
        *(float4*)&gb[1][g4] = p1;
        __syncthreads();

        {
            float gi = gb[0][t];
            float gf = gb[0][512 + t];
            float gg = gb[0][1024 + t];
            float go = gb[0][1536 + t];
            float iv  = 1.f / (1.f + expf(-gi));
            float fvv = 1.f / (1.f + expf(-gf));
            float gv  = tanhf(gg);
            float ov  = 1.f / (1.f + expf(-go));
            float cn = fvv * csr0 + iv * gv;
            float hn = ov * tanhf(cn);
            csr0 = cn;
            ((signed char*)hq[0])[t] = (signed char)(int)rintf(hn * 127.f);
            Lout[((size_t)(b0 + 0) * 512 + s) * 1024 + (dir << 9) + t] = f2b(hn);
        }
        {
            float gi = gb[1][t];
            float gf = gb[1][512 + t];
            float gg = gb[1][1024 + t];
            float go = gb[1][1536 + t];
            float iv  = 1.f / (1.f + expf(-gi));
            float fvv = 1.f / (1.f + expf(-gf));
            float gv  = tanhf(gg);
            float ov  = 1.f / (1.f + expf(-go));
            float cn = fvv * csr1 + iv * gv;
            float hn = ov * tanhf(cn);
            csr1 = cn;
            ((signed char*)hq[1])[t] = (signed char)(int)rintf(hn * 127.f);
            Lout[((size_t)(b0 + 1) * 512 + s) * 1024 + (dir << 9) + t] = f2b(hn);
        }
        __syncthreads();
    }
}
#endif  // HAVE_SDOT8

// --- Kernel 4: feats = Lout(bf16) @ W_out^T + b_out ------------------------
__global__ __launch_bounds__(256) void k_feats(const u16* __restrict__ Lout,
        const float* __restrict__ Wout, const float* __restrict__ bout,
        float* __restrict__ Ft) {
    __shared__ __align__(16) float Wl[12 * 1024];
    for (int i = threadIdx.x; i < 12 * 1024; i += 256) Wl[i] = Wout[i];
    __syncthreads();
    int wv = threadIdx.x >> 6, lane = threadIdx.x & 63;
    size_t row = (size_t)blockIdx.x * 4 + wv;
    const uint4* xr = (const uint4*)(Lout + row * 1024);
    float acc[12];
    #pragma unroll
    for (int tg = 0; tg < 12; ++tg) acc[tg] = 0.f;
    #pragma unroll
    for (int c = 0; c < 2; ++c) {
        int e8 = lane + (c << 6);
        uint4 xv = xr[e8];
        float x0 = flo(xv.x), x1 = fhi(xv.x);
        float x2 = flo(xv.y), x3 = fhi(xv.y);
        float x4 = flo(xv.z), x5 = fhi(xv.z);
        float x6 = flo(xv.w), x7 = fhi(xv.w);
        #pragma unroll
        for (int tg = 0; tg < 12; ++tg) {
            const float* wpt = &Wl[tg * 1024 + (e8 << 3)];
            float4 wa = *(const float4*)wpt;
            float4 wb = *(const float4*)(wpt + 4);
            acc[tg] += x0 * wa.x + x1 * wa.y + x2 * wa.z + x3 * wa.w
                     + x4 * wb.x + x5 * wb.y + x6 * wb.z + x7 * wb.w;
        }
    }
    #pragma unroll
    for (int tg = 0; tg < 12; ++tg) {
        #pragma unroll
        for (int off = 32; off > 0; off >>= 1)
            acc[tg] += __shfl_xor(acc[tg], off);
    }
    float v = 0.f;
    #pragma unroll
    for (int tg = 0; tg < 12; ++tg)
        if (lane == tg) v = acc[tg];
    if (lane < 12) Ft[row * 12 + lane] = v + bout[lane];
}

// --- Kernel 5: Viterbi per batch (1 wave). ---------------------------------
__global__ __launch_bounds__(64) void k_viterbi(const float* __restrict__ Ft,
        const float* __restrict__ trans, float* __restrict__ out) {
    int b = blockIdx.x;
    int lane = threadIdx.x;
    __shared__ unsigned char bps[512][12];
    float tr[12];
    #pragma unroll
    for (int p = 0; p < 12; ++p)
        tr[p] = (lane < 12) ? trans[lane * 12 + p] : 0.f;
    float fv = (lane == TAG_START) ? 0.f : NEGV;
    const float* fb = Ft + (size_t)b * 512 * 12;
    for (int s = 0; s < 512; ++s) {
        float m = -3.4e38f;
        int bp = 0;
        #pragma unroll
        for (int p = 0; p < 12; ++p) {
            float v = __shfl(fv, p) + tr[p];
            if (v > m) { m = v; bp = p; }
        }
        float feat = (lane < 12) ? fb[s * 12 + lane] : 0.f;
        fv = m + feat;
        if (lane < 12) bps[s][lane] = (unsigned char)bp;
    }
    float term = fv + ((lane < 12) ? trans[TAG_STOP * 12 + lane] : 0.f);
    __syncthreads();
    float best = -3.4e38f; int tag = 0;
    #pragma unroll
    for (int p = 0; p < 12; ++p) {
        float v = __shfl(term, p);
        if (v > best) { best = v; tag = p; }
    }
    if (lane == 0) {
        out[b] = best;
        int tg = tag;
        for (int s = 511; s >= 0; --s) {
            out[64 + (size_t)b * 512 + s] = (float)tg;
            tg = bps[s][tg];
        }
    }
}

extern "C" void kernel_launch(void* const* d_in, const int* in_sizes, int n_in,
                              void* d_out, int out_size, void* d_ws, size_t ws_size,
                              hipStream_t stream) {
    const int*   sent   = (const int*)  d_in[0];
    const float* emb    = (const float*)d_in[1];
    const float* W_ih_f = (const float*)d_in[2];
    const float* W_hh_f = (const float*)d_in[3];
    const float* b_f    = (const float*)d_in[4];
    const float* W_ih_b = (const float*)d_in[5];
    const float* W_hh_b = (const float*)d_in[6];
    const float* b_b    = (const float*)d_in[7];
    const float* W_out  = (const float*)d_in[8];
    const float* b_out  = (const float*)d_in[9];
    const float* trans  = (const float*)d_in[10];
    float* out = (float*)d_out;

    char* wsB = (char*)d_ws;
    size_t off = 0;
    uint32* Wn     = (uint32*)(wsB + off); off += 1048576;
    float*  sW     = (float*) (wsB + off); off += 16384;
    u16*    Wihb   = (u16*)   (wsB + off); off += 4194304;
    float*  biascat= (float*) (wsB + off); off += 16384;
    float*  Ft     = (float*) (wsB + off); off += 1572864;
    u16*    Lout   = (u16*)   (wsB + off); off += 67108864;
    size_t fixed = off;
    u16*    Gxc    = (u16*)   (wsB + off);

    int NB = 64;
    while (NB > 2 && fixed + (size_t)NB * 4194304ull > ws_size) NB >>= 1;

    k_packw<<<4096, 256, 0, stream>>>(W_ih_f, W_ih_b, b_f, b_b, Wihb, biascat);
    k_pack <<<4096, 64, 0, stream>>>(W_hh_f, W_hh_b, Wn, sW);
    for (int c = 0; c < 64; c += NB) {
        k_gemm<<<NB * 128, 256, 0, stream>>>(sent, emb, Wihb, biascat, Gxc, c);
        k_lstm<<<NB, 512, 0, stream>>>(Gxc, Wn, sW, Lout, c);
    }
    k_feats  <<<8192, 256, 0, stream>>>(Lout, W_out, b_out, Ft);
    k_viterbi<<<64, 64, 0, stream>>>(Ft, trans, out);
}